// Round 4
// baseline (2163.723 us; speedup 1.0000x reference)
//
#include <hip/hip_runtime.h>
#include <cfloat>

// ---- problem dims ----
#define NN    16380
#define RR    819
#define APR   20
#define KNB   16
#define HID   64
#define LAYERS 6
#define BINS  100
#define N64   (NN*HID)          // 1,048,320

// ---- mega-kernel geometry ----
#define ATB   32                // atoms per block
#define NBLK  512               // 512*32 = 16384 >= NN ; 2 blocks/CU co-resident
#define LDA   68                // padded stride for 64-wide LDS tiles
#define LDU   132               // padded stride for 128-wide LDS tile

// ---- workspace float offsets ----
#define OFF_KF0   0
#define OFF_VF0   (1*N64)
#define OFF_VV0   (2*N64)           // 3 planes
#define OFF_KF1   (5*N64)
#define OFF_VF1   (6*N64)
#define OFF_VV1   (7*N64)           // 3 planes
#define OFF_VG    (10*N64)          // v (3 planes), block-private
#define OFF_DIRN  (13*N64)          // N*48
#define OFF_C4    (OFF_DIRN + NN*48)
#define OFF_RES   (OFF_C4 + NN*4)
#define OFF_NBR   (OFF_RES + RR*64)
#define OFF_BINS  (OFF_NBR + NN*16)
#define OFF_BAR   (OFF_BINS + NN*16)   // 2 unsigned

__device__ __forceinline__ float gelu_f(float x) {
    float x3 = x*x*x;
    float t = tanhf(0.7978845608028654f*(x + 0.044715f*x3));
    return 0.5f*x*(1.0f+t);
}
__device__ __forceinline__ float sigmoid_f(float x) {
    return 1.0f/(1.0f + expf(-x));
}

// ---------------- pad coords to float4 ----------------
__global__ void pad4_kernel(const float* __restrict__ coords, float4* __restrict__ c4, int n) {
    int i = blockIdx.x*256 + threadIdx.x;
    if (i < n) c4[i] = make_float4(coords[3*i], coords[3*i+1], coords[3*i+2], 0.f);
}

// ---------------- kNN (BIT-IDENTICAL to round-3 passing version) ----------------
__global__ __launch_bounds__(1024) void knn_kernel(const float4* __restrict__ c4,
                                                   int* __restrict__ nbr, int* __restrict__ binsO,
                                                   float* __restrict__ dirn, int n) {
    __shared__ float4 tile[1024];
    int tid = threadIdx.x;
    int wave = tid >> 6, lane = tid & 63;
    int dst = blockIdx.x*16 + wave;
    bool wvalid = dst < n;
    int d = wvalid ? dst : 0;
    float4 cd = c4[d];
    float sqd = __fadd_rn(__fadd_rn(__fmul_rn(cd.x,cd.x), __fmul_rn(cd.y,cd.y)),
                          __fmul_rn(cd.z,cd.z));
    float dlist = FLT_MAX;  int ilist = -1;
    float vmax  = FLT_MAX;
    float vmaxf = FLT_MAX;
    int ntiles = (n + 1023) >> 10;
    for (int t = 0; t < ntiles; ++t) {
        __syncthreads();
        int sidx = (t<<10) + tid;
        tile[tid] = (sidx < n) ? c4[sidx] : make_float4(1e30f,1e30f,1e30f,0.f);
        __syncthreads();
        #pragma unroll 4
        for (int it = 0; it < 16; ++it) {
            int src = (t<<10) + (it<<6) + lane;
            float4 cs = tile[(it<<6) + lane];
            float fdx = cd.x-cs.x, fdy = cd.y-cs.y, fdz = cd.z-cs.z;
            float d2f = fdx*fdx + fdy*fdy + fdz*fdz;
            if (src == d) d2f = FLT_MAX;
            unsigned long long mask = __ballot(d2f < vmaxf);
            while (mask) {
                int lb = (int)__builtin_ctzll(mask);
                mask &= mask - 1;
                float csx = __shfl(cs.x, lb), csy = __shfl(cs.y, lb), csz = __shfl(cs.z, lb);
                int   ic  = __shfl(src, lb);
                float sqj = __fadd_rn(__fadd_rn(__fmul_rn(csx,csx), __fmul_rn(csy,csy)),
                                      __fmul_rn(csz,csz));
                float dt  = __fmul_rn(cd.x, csx);
                dt = __fmaf_rn(cd.y, csy, dt);
                dt = __fmaf_rn(cd.z, csz, dt);
                float dc = __fsub_rn(__fadd_rn(sqd, sqj), __fmul_rn(2.0f, dt));
                if (dc < vmax) {
                    float dp = __shfl_up(dlist, 1);
                    int   ip = __shfl_up(ilist, 1);
                    bool below = dc < dlist;
                    bool take  = below && (lane == 0 || dc >= dp);
                    if (lane < 16) {
                        dlist = below ? (take ? dc : dp) : dlist;
                        ilist = below ? (take ? ic : ip) : ilist;
                    }
                    vmax  = __shfl(dlist, 15);
                    vmaxf = vmax + 0.05f;
                }
            }
        }
    }
    if (wvalid && lane < 16) {
        int src = ilist;
        float4 cs = c4[src];
        float dx = __fsub_rn(cd.x, cs.x);
        float dy = __fsub_rn(cd.y, cs.y);
        float dz = __fsub_rn(cd.z, cs.z);
        float ss = __fadd_rn(__fadd_rn(__fmul_rn(dx,dx), __fmul_rn(dy,dy)),
                             __fmul_rn(dz,dz));
        float dd = __fsqrt_rn(__fadd_rn(ss, 1e-12f));
        nbr[dst*KNB + lane] = src;
        float bf = __fmul_rn(__fdiv_rn(dd, 10.0f), 100.0f);
        int b = (int)bf;
        b = min(max(b, 0), BINS-1);
        binsO[dst*KNB + lane] = b;
        dirn[dst*48 + lane*3 + 0] = __fdiv_rn(dx, dd);
        dirn[dst*48 + lane*3 + 1] = __fdiv_rn(dy, dd);
        dirn[dst*48 + lane*3 + 2] = __fdiv_rn(dz, dd);
    }
}

// ---------------- persistent fused model kernel ----------------
__global__ __launch_bounds__(256, 2) void mega_kernel(
    const int* __restrict__ aid, const int* __restrict__ rid, const int* __restrict__ eid,
    const int* __restrict__ ridx,
    const float* __restrict__ ea, const float* __restrict__ er, const float* __restrict__ ee,
    const float* __restrict__ Win, const float* __restrict__ Wq, const float* __restrict__ Wk,
    const float* __restrict__ Wv, const float* __restrict__ Wvec, const float* __restrict__ wdir,
    const float* __restrict__ dist_bias, const float* __restrict__ Wo, const float* __restrict__ W1,
    const float* __restrict__ W2, const float* __restrict__ Wg,
    float* __restrict__ ws)
{
    __shared__ __align__(16) float sS[ATB*LDA];    // persistent scalar features
    __shared__ __align__(16) float sH[ATB*LDA];    // h / q / h2
    __shared__ __align__(16) float sM[ATB*LDU];    // msg (cols 0..63) / u (128) / v-plane staging
    __shared__ __align__(16) float sW[64*64];      // weight staging

    float* kfb0 = ws+OFF_KF0; float* kfb1 = ws+OFF_KF1;
    float* vfb0 = ws+OFF_VF0; float* vfb1 = ws+OFF_VF1;
    float* vvb0 = ws+OFF_VV0; float* vvb1 = ws+OFF_VV1;
    float* vg   = ws+OFF_VG;
    const float* dirn = ws+OFF_DIRN;
    float* resb = ws+OFF_RES;
    const int* nbr  = (const int*)(ws+OFF_NBR);
    const int* bins = (const int*)(ws+OFF_BINS);
    unsigned* bar = (unsigned*)(ws+OFF_BAR);

    const int tid  = threadIdx.x;
    const int a0   = blockIdx.x * ATB;
    const int gi   = tid >> 4;     // 0..15 -> atoms gi, gi+16
    const int gj   = tid & 15;     // 4-col group
    const int lrow = tid >> 3;     // 0..31
    const int lsub = tid & 7;
    const int wv   = tid >> 6;
    const int lane = tid & 63;

    auto stageW = [&](const float* W) {
        const float4* src = (const float4*)W;
        float4* dst = (float4*)sW;
        #pragma unroll
        for (int r = 0; r < 4; ++r) dst[tid + 256*r] = src[tid + 256*r];
    };
    auto stageW1h = [&](const float* W1l, int h) {
        const float4* src = (const float4*)W1l;
        float4* dst = (float4*)sW;
        #pragma unroll
        for (int r = 0; r < 4; ++r) {
            int q = tid + 256*r;
            int row = q >> 4, c4i = q & 15;
            dst[q] = src[row*32 + h*16 + c4i];
        }
    };
    auto do_gemm = [&](const float* sA, int lda, int ko, float4& c0, float4& c1) {
        const float* a0p = sA + gi*lda + ko;
        const float* a1p = sA + (gi+16)*lda + ko;
        const float* wr  = sW + gj*4;
        #pragma unroll 8
        for (int k = 0; k < 64; ++k) {
            float av0 = a0p[k], av1 = a1p[k];
            float4 w = *(const float4*)(wr + k*64);
            c0.x = fmaf(av0,w.x,c0.x); c0.y = fmaf(av0,w.y,c0.y);
            c0.z = fmaf(av0,w.z,c0.z); c0.w = fmaf(av0,w.w,c0.w);
            c1.x = fmaf(av1,w.x,c1.x); c1.y = fmaf(av1,w.y,c1.y);
            c1.z = fmaf(av1,w.z,c1.z); c1.w = fmaf(av1,w.w,c1.w);
        }
    };
    auto do_ln = [&](const float* src, float* dst) {
        const float* sp = src + lrow*LDA + lsub*8;
        float v[8]; float s1 = 0.f;
        #pragma unroll
        for (int e = 0; e < 8; ++e) { v[e] = sp[e]; s1 += v[e]; }
        s1 += __shfl_xor(s1,1); s1 += __shfl_xor(s1,2); s1 += __shfl_xor(s1,4);
        float mean = s1*(1.0f/64.0f);
        float s2 = 0.f;
        #pragma unroll
        for (int e = 0; e < 8; ++e) { float t = v[e]-mean; s2 += t*t; }
        s2 += __shfl_xor(s2,1); s2 += __shfl_xor(s2,2); s2 += __shfl_xor(s2,4);
        float sc = 1.0f/sqrtf(s2*(1.0f/64.0f)+1e-5f);
        float* dp = dst + lrow*LDA + lsub*8;
        #pragma unroll
        for (int e = 0; e < 8; ++e) dp[e] = (v[e]-mean)*sc;
    };
    auto store_g = [&](float* base, float4 c0, float4 c1) {
        int g0 = a0+gi, g1 = a0+gi+16;
        if (g0 < NN) *(float4*)(base + g0*64 + gj*4) = c0;
        if (g1 < NN) *(float4*)(base + g1*64 + gj*4) = c1;
    };
    auto grid_sync = [&]() {
        __syncthreads();
        __threadfence();
        if (tid == 0) {
            unsigned* cnt = bar; unsigned* gen = bar+1;
            unsigned g = __hip_atomic_load(gen, __ATOMIC_RELAXED, __HIP_MEMORY_SCOPE_AGENT);
            unsigned arr = __hip_atomic_fetch_add(cnt, 1u, __ATOMIC_ACQ_REL, __HIP_MEMORY_SCOPE_AGENT);
            if (arr == (unsigned)(NBLK-1)) {
                __hip_atomic_store(cnt, 0u, __ATOMIC_RELAXED, __HIP_MEMORY_SCOPE_AGENT);
                __hip_atomic_fetch_add(gen, 1u, __ATOMIC_RELEASE, __HIP_MEMORY_SCOPE_AGENT);
            } else {
                while (__hip_atomic_load(gen, __ATOMIC_ACQUIRE, __HIP_MEMORY_SCOPE_AGENT) == g) {}
            }
        }
        __syncthreads();
        __threadfence();
    };

    // ---- stage 0: embeddings -> sH ; zero own v ; s = feat @ Win ----
    {
        int ga = a0 + lrow;
        float vals[8];
        if (ga < NN) {
            int a_ = aid[ga], r_ = rid[ga], e_ = eid[ga];
            #pragma unroll
            for (int e = 0; e < 8; ++e) {
                int c = lsub*8 + e;
                float x;
                if (c < 32)      x = ea[a_*32 + c];
                else if (c < 48) x = er[r_*16 + (c-32)];
                else             x = ee[e_*16 + (c-48)];
                vals[e] = x;
            }
            float4 z = make_float4(0.f,0.f,0.f,0.f);
            #pragma unroll
            for (int p = 0; p < 3; ++p) {
                float4* vp = (float4*)(vg + (size_t)p*N64 + (size_t)ga*64);
                vp[lsub*2] = z; vp[lsub*2+1] = z;
            }
        } else {
            #pragma unroll
            for (int e = 0; e < 8; ++e) vals[e] = 0.f;
        }
        #pragma unroll
        for (int e = 0; e < 8; ++e) sH[lrow*LDA + lsub*8 + e] = vals[e];
    }
    __syncthreads();
    stageW(Win);
    __syncthreads();
    {
        float4 c0 = make_float4(0,0,0,0), c1 = c0;
        do_gemm(sH, LDA, 0, c0, c1);
        *(float4*)(sS + gi*LDA + gj*4)      = c0;
        *(float4*)(sS + (gi+16)*LDA + gj*4) = c1;
    }
    __syncthreads();

    // ---- layers ----
    for (int l = 0; l < LAYERS; ++l) {
        const float* Wq_l = Wq + l*4096;  const float* Wk_l = Wk + l*4096;
        const float* Wv_l = Wv + l*4096;  const float* Wc_l = Wvec + l*4096;
        const float* Wo_l = Wo + l*4096;  const float* Wg_l = Wg + l*4096;
        const float* W1_l = W1 + l*8192;  const float* W2_l = W2 + l*8192;
        const float* db_l = dist_bias + l*BINS*8;
        const float* wd_l = wdir + l*64;
        float* kfg = (l&1) ? kfb1 : kfb0;
        float* vfg = (l&1) ? vfb1 : vfb0;
        float* vvg = (l&1) ? vvb1 : vvb0;

        // h = LN(s)
        do_ln(sS, sH);
        __syncthreads();

        // kf = h @ Wk  -> global
        stageW(Wk_l); __syncthreads();
        { float4 c0 = make_float4(0,0,0,0), c1 = c0;
          do_gemm(sH, LDA, 0, c0, c1); store_g(kfg, c0, c1); }
        __syncthreads();
        // vf = h @ Wv  -> global
        stageW(Wv_l); __syncthreads();
        { float4 c0 = make_float4(0,0,0,0), c1 = c0;
          do_gemm(sH, LDA, 0, c0, c1); store_g(vfg, c0, c1); }
        __syncthreads();
        // vv_p = v_p @ Wvec  -> global (3 planes)
        stageW(Wc_l); __syncthreads();
        for (int p = 0; p < 3; ++p) {
            {   // stage own v plane into sM
                int ga = a0 + lrow;
                float4 z = make_float4(0,0,0,0);
                float4 x0 = z, x1 = z;
                if (ga < NN) {
                    const float4* vp = (const float4*)(vg + (size_t)p*N64 + (size_t)ga*64);
                    x0 = vp[lsub*2]; x1 = vp[lsub*2+1];
                }
                float4* mp = (float4*)(sM + lrow*LDU);
                mp[lsub*2] = x0; mp[lsub*2+1] = x1;
            }
            __syncthreads();
            { float4 c0 = make_float4(0,0,0,0), c1 = c0;
              do_gemm(sM, LDU, 0, c0, c1); store_g(vvg + (size_t)p*N64, c0, c1); }
            __syncthreads();
        }
        // q = h @ Wq -> regs -> sH (overwrite h; h dead after this)
        stageW(Wq_l); __syncthreads();
        {
            float4 q0 = make_float4(0,0,0,0), q1 = q0;
            do_gemm(sH, LDA, 0, q0, q1);
            __syncthreads();
            *(float4*)(sH + gi*LDA + gj*4)      = q0;
            *(float4*)(sH + (gi+16)*LDA + gj*4) = q1;
        }

        // all blocks' kf/vf/vv visible
        grid_sync();

        // ---- attention: wave handles 8 atoms, lane = channel ----
        {
            float wd = wd_l[lane];
            for (int aa = 0; aa < 8; ++aa) {
                int la = wv*8 + aa;
                int ga = a0 + la;
                if (ga >= NN) break;
                float qh = sH[la*LDA + lane];
                float lg[KNB]; int nb[KNB];
                #pragma unroll
                for (int k = 0; k < KNB; ++k) {
                    int j = nbr[ga*KNB + k];
                    nb[k] = j;
                    float t = qh * kfg[(size_t)j*64 + lane];
                    t += __shfl_xor(t,1); t += __shfl_xor(t,2); t += __shfl_xor(t,4);
                    lg[k] = t*0.35355339059327373f + db_l[bins[ga*KNB+k]*8 + (lane>>3)];
                }
                float m = lg[0];
                #pragma unroll
                for (int k = 1; k < KNB; ++k) m = fmaxf(m, lg[k]);
                float ssum = 0.f;
                #pragma unroll
                for (int k = 0; k < KNB; ++k) { lg[k] = expf(lg[k]-m); ssum += lg[k]; }
                float inv = 1.0f/ssum;
                float mh=0.f, b0=0.f, b1=0.f, b2=0.f, s0=0.f, s1=0.f, s2=0.f;
                #pragma unroll
                for (int k = 0; k < KNB; ++k) {
                    float w = lg[k]*inv; int j = nb[k];
                    mh += w * vfg[(size_t)j*64 + lane];
                    b0 += w * vvg[(size_t)j*64 + lane];
                    b1 += w * vvg[(size_t)N64 + (size_t)j*64 + lane];
                    b2 += w * vvg[2*(size_t)N64 + (size_t)j*64 + lane];
                    s0 += w * dirn[ga*48 + k*3 + 0];
                    s1 += w * dirn[ga*48 + k*3 + 1];
                    s2 += w * dirn[ga*48 + k*3 + 2];
                }
                sM[la*LDU + lane] = mh;
                vg[(size_t)ga*64 + lane]                    += b0 + wd*s0;
                vg[(size_t)N64 + (size_t)ga*64 + lane]      += b1 + wd*s1;
                vg[2*(size_t)N64 + (size_t)ga*64 + lane]    += b2 + wd*s2;
            }
        }
        __syncthreads();

        // s += msg @ Wo
        stageW(Wo_l); __syncthreads();
        {
            float4 c0 = *(float4*)(sS + gi*LDA + gj*4);
            float4 c1 = *(float4*)(sS + (gi+16)*LDA + gj*4);
            do_gemm(sM, LDU, 0, c0, c1);
            *(float4*)(sS + gi*LDA + gj*4)      = c0;
            *(float4*)(sS + (gi+16)*LDA + gj*4) = c1;
        }
        __syncthreads();

        // h2 = LN(s)
        do_ln(sS, sH);
        __syncthreads();

        // v *= sigmoid(h2 @ Wg)
        stageW(Wg_l); __syncthreads();
        {
            float4 c0 = make_float4(0,0,0,0), c1 = c0;
            do_gemm(sH, LDA, 0, c0, c1);
            c0.x = sigmoid_f(c0.x); c0.y = sigmoid_f(c0.y); c0.z = sigmoid_f(c0.z); c0.w = sigmoid_f(c0.w);
            c1.x = sigmoid_f(c1.x); c1.y = sigmoid_f(c1.y); c1.z = sigmoid_f(c1.z); c1.w = sigmoid_f(c1.w);
            int g0 = a0+gi, g1 = a0+gi+16;
            #pragma unroll
            for (int p = 0; p < 3; ++p) {
                if (g0 < NN) {
                    float4* vp = (float4*)(vg + (size_t)p*N64 + (size_t)g0*64 + gj*4);
                    float4 x = *vp; x.x*=c0.x; x.y*=c0.y; x.z*=c0.z; x.w*=c0.w; *vp = x;
                }
                if (g1 < NN) {
                    float4* vp = (float4*)(vg + (size_t)p*N64 + (size_t)g1*64 + gj*4);
                    float4 x = *vp; x.x*=c1.x; x.y*=c1.y; x.z*=c1.z; x.w*=c1.w; *vp = x;
                }
            }
        }
        __syncthreads();

        // u = gelu(h2 @ W1)  (two 64-col halves into sM)
        stageW1h(W1_l, 0); __syncthreads();
        {
            float4 c0 = make_float4(0,0,0,0), c1 = c0;
            do_gemm(sH, LDA, 0, c0, c1);
            c0.x=gelu_f(c0.x); c0.y=gelu_f(c0.y); c0.z=gelu_f(c0.z); c0.w=gelu_f(c0.w);
            c1.x=gelu_f(c1.x); c1.y=gelu_f(c1.y); c1.z=gelu_f(c1.z); c1.w=gelu_f(c1.w);
            __syncthreads();
            *(float4*)(sM + gi*LDU + gj*4)      = c0;
            *(float4*)(sM + (gi+16)*LDU + gj*4) = c1;
        }
        stageW1h(W1_l, 1); __syncthreads();
        {
            float4 c0 = make_float4(0,0,0,0), c1 = c0;
            do_gemm(sH, LDA, 0, c0, c1);
            c0.x=gelu_f(c0.x); c0.y=gelu_f(c0.y); c0.z=gelu_f(c0.z); c0.w=gelu_f(c0.w);
            c1.x=gelu_f(c1.x); c1.y=gelu_f(c1.y); c1.z=gelu_f(c1.z); c1.w=gelu_f(c1.w);
            __syncthreads();
            *(float4*)(sM + gi*LDU + 64 + gj*4)      = c0;
            *(float4*)(sM + (gi+16)*LDU + 64 + gj*4) = c1;
        }
        // s += u @ W2  (two 64-row K halves)
        stageW(W2_l); __syncthreads();
        {
            float4 c0 = *(float4*)(sS + gi*LDA + gj*4);
            float4 c1 = *(float4*)(sS + (gi+16)*LDA + gj*4);
            do_gemm(sM, LDU, 0, c0, c1);
            __syncthreads();
            stageW(W2_l + 4096); __syncthreads();
            do_gemm(sM, LDU, 64, c0, c1);
            *(float4*)(sS + gi*LDA + gj*4)      = c0;
            *(float4*)(sS + (gi+16)*LDA + gj*4) = c1;
        }
        __syncthreads();
    }

    // ---- residue pooling (atomic) ----
    {
        int ga = a0 + lrow;
        if (ga < NN) {
            int r = ridx[ga];
            #pragma unroll
            for (int e = 0; e < 8; ++e)
                atomicAdd(&resb[r*64 + lsub*8 + e], sS[lrow*LDA + lsub*8 + e]);
        }
    }
}

// ---------------- head ----------------
__global__ void head_kernel(const float* __restrict__ res, const float* __restrict__ Wout,
                            const float* __restrict__ bout, float* __restrict__ out, int r_total) {
    int wave = threadIdx.x >> 6, lane = threadIdx.x & 63;
    int r = blockIdx.x*4 + wave;
    if (r >= r_total) return;
    float p = res[r*HID + lane] * (1.0f/APR);
    float o0 = p * Wout[lane*2 + 0];
    float o1 = p * Wout[lane*2 + 1];
    #pragma unroll
    for (int off = 1; off < 64; off <<= 1) { o0 += __shfl_xor(o0, off); o1 += __shfl_xor(o1, off); }
    if (lane == 0) { out[r*2+0] = o0 + bout[0]; out[r*2+1] = o1 + bout[1]; }
}

// ---------------- launcher ----------------
extern "C" void kernel_launch(void* const* d_in, const int* in_sizes, int n_in,
                              void* d_out, int out_size, void* d_ws, size_t ws_size,
                              hipStream_t stream) {
    const float* coords    = (const float*)d_in[0];
    const int*   atom_ids  = (const int*)d_in[1];
    const int*   res_ids   = (const int*)d_in[2];
    const int*   elem_ids  = (const int*)d_in[3];
    const int*   ridx      = (const int*)d_in[4];
    const float* emb_atom  = (const float*)d_in[5];
    const float* emb_res   = (const float*)d_in[6];
    const float* emb_elem  = (const float*)d_in[7];
    const float* Win       = (const float*)d_in[8];
    const float* Wq        = (const float*)d_in[9];
    const float* Wk        = (const float*)d_in[10];
    const float* Wv        = (const float*)d_in[11];
    const float* Wvec      = (const float*)d_in[12];
    const float* wdir      = (const float*)d_in[13];
    const float* dist_bias = (const float*)d_in[14];
    const float* Wo        = (const float*)d_in[15];
    const float* W1        = (const float*)d_in[16];
    const float* W2        = (const float*)d_in[17];
    const float* Wg        = (const float*)d_in[18];
    const float* Wout      = (const float*)d_in[19];
    const float* bout      = (const float*)d_in[20];
    float* out = (float*)d_out;

    float* ws = (float*)d_ws;
    float4* c4  = (float4*)(ws + OFF_C4);
    float* resb = ws + OFF_RES;
    int* nbr    = (int*)(ws + OFF_NBR);
    int* binsb  = (int*)(ws + OFF_BINS);
    float* dirn = ws + OFF_DIRN;

    hipMemsetAsync(resb, 0, (size_t)RR*HID*sizeof(float), stream);
    hipMemsetAsync(ws + OFF_BAR, 0, 2*sizeof(unsigned), stream);

    pad4_kernel<<<(NN+255)/256, 256, 0, stream>>>(coords, c4, NN);
    knn_kernel<<<(NN+15)/16, 1024, 0, stream>>>(c4, nbr, binsb, dirn, NN);
    mega_kernel<<<NBLK, 256, 0, stream>>>(atom_ids, res_ids, elem_ids, ridx,
                                          emb_atom, emb_res, emb_elem,
                                          Win, Wq, Wk, Wv, Wvec, wdir, dist_bias,
                                          Wo, W1, W2, Wg, ws);
    head_kernel<<<(RR+3)/4, 256, 0, stream>>>(resb, Wout, bout, out, RR);
}

// Round 5
// 791.517 us; speedup vs baseline: 2.7336x; 2.7336x over previous
//
#include <hip/hip_runtime.h>
#include <cfloat>

// ---- problem dims ----
#define NN    16380
#define RR    819
#define APR   20
#define KNB   16
#define HID   64
#define LAYERS 6
#define BINS  100
#define N64   (NN*HID)

// ---- geometry ----
#define ATB   32
#define NBLK  512               // 512*32 = 16384 >= NN
#define LDA   68
#define LDU   132

// ---- workspace float offsets ----
#define OFF_QA    0
#define OFF_KA    (1*N64)
#define OFF_FA    (2*N64)
#define OFF_QB    (3*N64)
#define OFF_KB    (4*N64)
#define OFF_FB    (5*N64)
#define OFF_VA    (6*N64)           // 3 planes
#define OFF_VB    (9*N64)           // 3 planes
#define OFF_S     (12*N64)
#define OFF_DIRN  (13*N64)          // N*48
#define OFF_C4    (OFF_DIRN + NN*48)
#define OFF_RES   (OFF_C4 + NN*4)
#define OFF_NBR   (OFF_RES + RR*64)
#define OFF_BINS  (OFF_NBR + NN*16)

__device__ __forceinline__ float gelu_f(float x) {
    float x3 = x*x*x;
    float t = tanhf(0.7978845608028654f*(x + 0.044715f*x3));
    return 0.5f*x*(1.0f+t);
}
__device__ __forceinline__ float sigmoid_f(float x) {
    return 1.0f/(1.0f + expf(-x));
}

// ---------------- pad coords to float4 ----------------
__global__ void pad4_kernel(const float* __restrict__ coords, float4* __restrict__ c4, int n) {
    int i = blockIdx.x*256 + threadIdx.x;
    if (i < n) c4[i] = make_float4(coords[3*i], coords[3*i+1], coords[3*i+2], 0.f);
}

// ---------------- kNN: round-3 selection semantics + seeded prefilter ----------------
__global__ __launch_bounds__(1024) void knn_kernel(const float4* __restrict__ c4,
                                                   int* __restrict__ nbr, int* __restrict__ binsO,
                                                   float* __restrict__ dirn, int n) {
    __shared__ float4 tile[1024];
    int tid = threadIdx.x;
    int lane = tid & 63;
    int dst = blockIdx.x*16 + (tid >> 6);
    bool wvalid = dst < n;
    int d = wvalid ? dst : 0;
    float4 cd = c4[d];
    float sqd = __fadd_rn(__fadd_rn(__fmul_rn(cd.x,cd.x), __fmul_rn(cd.y,cd.y)),
                          __fmul_rn(cd.z,cd.z));
    float dlist = FLT_MAX;  int ilist = -1;
    float vmax  = FLT_MAX;
    float vmaxf = FLT_MAX;

    // --- seed pre-pass on tile 0: T = wave-max of lane-mins (>= true d16) ---
    {
        tile[tid] = (tid < n) ? c4[tid] : make_float4(1e30f,1e30f,1e30f,0.f);
        __syncthreads();
        float mymin = FLT_MAX;
        #pragma unroll
        for (int it = 0; it < 16; ++it) {
            int src = (it<<6) + lane;
            float4 cs = tile[(it<<6) + lane];
            float fdx = cd.x-cs.x, fdy = cd.y-cs.y, fdz = cd.z-cs.z;
            float d2f = fdx*fdx + fdy*fdy + fdz*fdz;
            if (src == d) d2f = FLT_MAX;
            mymin = fminf(mymin, d2f);
        }
        #pragma unroll
        for (int off = 1; off < 64; off <<= 1) mymin = fmaxf(mymin, __shfl_xor(mymin, off));
        vmaxf = mymin + 0.05f;
    }

    int ntiles = (n + 1023) >> 10;
    for (int t = 0; t < ntiles; ++t) {
        __syncthreads();
        int sidx = (t<<10) + tid;
        tile[tid] = (sidx < n) ? c4[sidx] : make_float4(1e30f,1e30f,1e30f,0.f);
        __syncthreads();
        #pragma unroll 4
        for (int it = 0; it < 16; ++it) {
            int src = (t<<10) + (it<<6) + lane;
            float4 cs = tile[(it<<6) + lane];
            float fdx = cd.x-cs.x, fdy = cd.y-cs.y, fdz = cd.z-cs.z;
            float d2f = fdx*fdx + fdy*fdy + fdz*fdz;
            if (src == d) d2f = FLT_MAX;
            unsigned long long mask = __ballot(d2f < vmaxf);
            while (mask) {
                int lb = (int)__builtin_ctzll(mask);
                mask &= mask - 1;
                float csx = __shfl(cs.x, lb), csy = __shfl(cs.y, lb), csz = __shfl(cs.z, lb);
                int   ic  = __shfl(src, lb);
                float sqj = __fadd_rn(__fadd_rn(__fmul_rn(csx,csx), __fmul_rn(csy,csy)),
                                      __fmul_rn(csz,csz));
                float dt  = __fmul_rn(cd.x, csx);
                dt = __fmaf_rn(cd.y, csy, dt);
                dt = __fmaf_rn(cd.z, csz, dt);
                float dc = __fsub_rn(__fadd_rn(sqd, sqj), __fmul_rn(2.0f, dt));
                if (dc < vmax) {
                    float dp = __shfl_up(dlist, 1);
                    int   ip = __shfl_up(ilist, 1);
                    bool below = dc < dlist;
                    bool take  = below && (lane == 0 || dc >= dp);
                    if (lane < 16) {
                        dlist = below ? (take ? dc : dp) : dlist;
                        ilist = below ? (take ? ic : ip) : ilist;
                    }
                    vmax  = __shfl(dlist, 15);
                    vmaxf = fminf(vmaxf, vmax + 0.05f);
                }
            }
        }
    }
    if (wvalid && lane < 16) {
        int src = ilist;
        float4 cs = c4[src];
        float dx = __fsub_rn(cd.x, cs.x);
        float dy = __fsub_rn(cd.y, cs.y);
        float dz = __fsub_rn(cd.z, cs.z);
        float ss = __fadd_rn(__fadd_rn(__fmul_rn(dx,dx), __fmul_rn(dy,dy)),
                             __fmul_rn(dz,dz));
        float dd = __fsqrt_rn(__fadd_rn(ss, 1e-12f));
        nbr[dst*KNB + lane] = src;
        float bf = __fmul_rn(__fdiv_rn(dd, 10.0f), 100.0f);
        int b = (int)bf;
        b = min(max(b, 0), BINS-1);
        binsO[dst*KNB + lane] = b;
        dirn[dst*48 + lane*3 + 0] = __fdiv_rn(dx, dd);
        dirn[dst*48 + lane*3 + 1] = __fdiv_rn(dy, dd);
        dirn[dst*48 + lane*3 + 2] = __fdiv_rn(dz, dd);
    }
}

// ======== shared device helpers (macro-free, inlined per kernel via lambdas) ========

// ---------------- prologue: feat -> s = feat@Win; q/k/vf layer0 ----------------
__global__ __launch_bounds__(256) void prologue_kernel(
    const int* __restrict__ aid, const int* __restrict__ rid, const int* __restrict__ eid,
    const float* __restrict__ ea, const float* __restrict__ er, const float* __restrict__ ee,
    const float* __restrict__ Win, const float* __restrict__ Wq, const float* __restrict__ Wk,
    const float* __restrict__ Wv,
    float* __restrict__ sg, float* __restrict__ qout, float* __restrict__ kout,
    float* __restrict__ vfout)
{
    __shared__ __align__(16) float sS[ATB*LDA];
    __shared__ __align__(16) float sH[ATB*LDA];
    __shared__ __align__(16) float sW[4096];
    const int tid = threadIdx.x;
    const int a0 = blockIdx.x*ATB;
    const int gi = tid>>4, gj = tid&15;
    const int lrow = tid>>3, lsub = tid&7;

    auto stageW = [&](const float* W) {
        const float4* src = (const float4*)W; float4* dst = (float4*)sW;
        #pragma unroll
        for (int r = 0; r < 4; ++r) dst[tid + 256*r] = src[tid + 256*r];
    };
    auto do_gemm = [&](const float* sA, float4& c0, float4& c1) {
        const float* a0p = sA + gi*LDA;
        const float* a1p = sA + (gi+16)*LDA;
        const float* wr  = sW + gj*4;
        #pragma unroll 8
        for (int k = 0; k < 64; ++k) {
            float av0 = a0p[k], av1 = a1p[k];
            float4 w = *(const float4*)(wr + k*64);
            c0.x = fmaf(av0,w.x,c0.x); c0.y = fmaf(av0,w.y,c0.y);
            c0.z = fmaf(av0,w.z,c0.z); c0.w = fmaf(av0,w.w,c0.w);
            c1.x = fmaf(av1,w.x,c1.x); c1.y = fmaf(av1,w.y,c1.y);
            c1.z = fmaf(av1,w.z,c1.z); c1.w = fmaf(av1,w.w,c1.w);
        }
    };
    auto do_ln = [&](const float* src, float* dst) {
        const float* sp = src + lrow*LDA + lsub*8;
        float v[8]; float s1 = 0.f;
        #pragma unroll
        for (int e = 0; e < 8; ++e) { v[e] = sp[e]; s1 += v[e]; }
        s1 += __shfl_xor(s1,1); s1 += __shfl_xor(s1,2); s1 += __shfl_xor(s1,4);
        float mean = s1*(1.0f/64.0f);
        float s2 = 0.f;
        #pragma unroll
        for (int e = 0; e < 8; ++e) { float t = v[e]-mean; s2 += t*t; }
        s2 += __shfl_xor(s2,1); s2 += __shfl_xor(s2,2); s2 += __shfl_xor(s2,4);
        float sc = 1.0f/sqrtf(s2*(1.0f/64.0f)+1e-5f);
        float* dp = dst + lrow*LDA + lsub*8;
        #pragma unroll
        for (int e = 0; e < 8; ++e) dp[e] = (v[e]-mean)*sc;
    };
    auto store_g = [&](float* base, float4 c0, float4 c1) {
        int g0 = a0+gi, g1 = a0+gi+16;
        if (g0 < NN) *(float4*)(base + (size_t)g0*64 + gj*4) = c0;
        if (g1 < NN) *(float4*)(base + (size_t)g1*64 + gj*4) = c1;
    };

    // feat -> sH
    {
        int ga = a0 + lrow;
        #pragma unroll
        for (int e = 0; e < 8; ++e) {
            int c = lsub*8 + e;
            float x = 0.f;
            if (ga < NN) {
                if (c < 32)      x = ea[aid[ga]*32 + c];
                else if (c < 48) x = er[rid[ga]*16 + (c-32)];
                else             x = ee[eid[ga]*16 + (c-48)];
            }
            sH[lrow*LDA + c] = x;
        }
    }
    __syncthreads();
    stageW(Win); __syncthreads();
    {
        float4 c0 = make_float4(0,0,0,0), c1 = c0;
        do_gemm(sH, c0, c1);
        *(float4*)(sS + gi*LDA + gj*4)      = c0;
        *(float4*)(sS + (gi+16)*LDA + gj*4) = c1;
        store_g(sg, c0, c1);
    }
    __syncthreads();
    do_ln(sS, sH);
    __syncthreads();
    stageW(Wk); __syncthreads();
    { float4 c0 = make_float4(0,0,0,0), c1 = c0; do_gemm(sH, c0, c1); store_g(kout, c0, c1); }
    __syncthreads();
    stageW(Wv); __syncthreads();
    { float4 c0 = make_float4(0,0,0,0), c1 = c0; do_gemm(sH, c0, c1); store_g(vfout, c0, c1); }
    __syncthreads();
    stageW(Wq); __syncthreads();
    { float4 c0 = make_float4(0,0,0,0), c1 = c0; do_gemm(sH, c0, c1); store_g(qout, c0, c1); }
}

// ---------------- fused layer kernel ----------------
__global__ __launch_bounds__(256) void layer_kernel(
    const float* __restrict__ qin, const float* __restrict__ kin, const float* __restrict__ vfin,
    float* __restrict__ qout, float* __restrict__ kout, float* __restrict__ vfout,
    const float* __restrict__ vin, float* __restrict__ vout,
    float* __restrict__ sg, const float* __restrict__ dirn,
    const int* __restrict__ nbr, const int* __restrict__ bins,
    float* __restrict__ resb, const int* __restrict__ ridx,
    const float* __restrict__ Wvec, const float* __restrict__ wdir,
    const float* __restrict__ dist_bias,
    const float* __restrict__ Wo, const float* __restrict__ W1, const float* __restrict__ W2,
    const float* __restrict__ Wg, const float* __restrict__ Wq, const float* __restrict__ Wk,
    const float* __restrict__ Wv, int l)
{
    __shared__ __align__(16) float sS[ATB*LDA];     // s
    __shared__ __align__(16) float sH[ATB*LDA];     // h2 / next-h
    __shared__ __align__(16) float sM[ATB*LDU];     // msg then u
    __shared__ __align__(16) float sVA[3][ATB*LDA]; // raw v aggregates
    __shared__ __align__(16) float sW[4096];
    __shared__ float sDS[ATB*24];                   // [atom][p*8+head] dirn sums

    const int tid = threadIdx.x;
    const int a0 = blockIdx.x*ATB;
    const int gi = tid>>4, gj = tid&15;
    const int lrow = tid>>3, lsub = tid&7;
    const int wv = tid>>6, lane = tid&63;

    const float* Wo_l = Wo + l*4096;
    const float* Wg_l = Wg + l*4096;
    const float* Wc_l = Wvec + l*4096;
    const float* W1_l = W1 + l*8192;
    const float* W2_l = W2 + l*8192;
    const float* db_l = dist_bias + l*BINS*8;
    const float* wd_l = wdir + l*64;

    auto stageW = [&](const float* W) {
        const float4* src = (const float4*)W; float4* dst = (float4*)sW;
        #pragma unroll
        for (int r = 0; r < 4; ++r) dst[tid + 256*r] = src[tid + 256*r];
    };
    auto stageW1h = [&](const float* W1l, int h) {
        const float4* src = (const float4*)W1l; float4* dst = (float4*)sW;
        #pragma unroll
        for (int r = 0; r < 4; ++r) {
            int q = tid + 256*r;
            int row = q >> 4, c4i = q & 15;
            dst[q] = src[row*32 + h*16 + c4i];
        }
    };
    auto do_gemm = [&](const float* sA, int lda, int ko, float4& c0, float4& c1) {
        const float* a0p = sA + gi*lda + ko;
        const float* a1p = sA + (gi+16)*lda + ko;
        const float* wr  = sW + gj*4;
        #pragma unroll 8
        for (int k = 0; k < 64; ++k) {
            float av0 = a0p[k], av1 = a1p[k];
            float4 w = *(const float4*)(wr + k*64);
            c0.x = fmaf(av0,w.x,c0.x); c0.y = fmaf(av0,w.y,c0.y);
            c0.z = fmaf(av0,w.z,c0.z); c0.w = fmaf(av0,w.w,c0.w);
            c1.x = fmaf(av1,w.x,c1.x); c1.y = fmaf(av1,w.y,c1.y);
            c1.z = fmaf(av1,w.z,c1.z); c1.w = fmaf(av1,w.w,c1.w);
        }
    };
    auto do_ln = [&](const float* src, float* dst) {
        const float* sp = src + lrow*LDA + lsub*8;
        float v[8]; float s1 = 0.f;
        #pragma unroll
        for (int e = 0; e < 8; ++e) { v[e] = sp[e]; s1 += v[e]; }
        s1 += __shfl_xor(s1,1); s1 += __shfl_xor(s1,2); s1 += __shfl_xor(s1,4);
        float mean = s1*(1.0f/64.0f);
        float s2 = 0.f;
        #pragma unroll
        for (int e = 0; e < 8; ++e) { float t = v[e]-mean; s2 += t*t; }
        s2 += __shfl_xor(s2,1); s2 += __shfl_xor(s2,2); s2 += __shfl_xor(s2,4);
        float sc = 1.0f/sqrtf(s2*(1.0f/64.0f)+1e-5f);
        float* dp = dst + lrow*LDA + lsub*8;
        #pragma unroll
        for (int e = 0; e < 8; ++e) dp[e] = (v[e]-mean)*sc;
    };
    auto store_g = [&](float* base, float4 c0, float4 c1) {
        int g0 = a0+gi, g1 = a0+gi+16;
        if (g0 < NN) *(float4*)(base + (size_t)g0*64 + gj*4) = c0;
        if (g1 < NN) *(float4*)(base + (size_t)g1*64 + gj*4) = c1;
    };

    // ---- P0: load s ----
    {
        int ga = a0 + lrow;
        float4 z = make_float4(0,0,0,0);
        float4 x0 = z, x1 = z;
        if (ga < NN) {
            const float4* sp = (const float4*)(sg + (size_t)ga*64);
            x0 = sp[lsub*2]; x1 = sp[lsub*2+1];
        }
        float4* dp = (float4*)(sS + lrow*LDA);
        dp[lsub*2] = x0; dp[lsub*2+1] = x1;
    }

    // ---- P1: attention ----
    for (int aa = 0; aa < 8; ++aa) {
        int la = wv*8 + aa;
        int ga = a0 + la;
        if (ga >= NN) break;
        float qh = qin[(size_t)ga*64 + lane];
        float lg[KNB]; int nb[KNB];
        #pragma unroll
        for (int k = 0; k < KNB; ++k) {
            int j = nbr[ga*KNB + k];
            nb[k] = j;
            float t = qh * kin[(size_t)j*64 + lane];
            t += __shfl_xor(t,1); t += __shfl_xor(t,2); t += __shfl_xor(t,4);
            lg[k] = t*0.35355339059327373f + db_l[bins[ga*KNB+k]*8 + (lane>>3)];
        }
        float m = lg[0];
        #pragma unroll
        for (int k = 1; k < KNB; ++k) m = fmaxf(m, lg[k]);
        float ssum = 0.f;
        #pragma unroll
        for (int k = 0; k < KNB; ++k) { lg[k] = expf(lg[k]-m); ssum += lg[k]; }
        float inv = 1.0f/ssum;
        float mh=0.f, b0=0.f, b1=0.f, b2=0.f, s0=0.f, s1=0.f, s2=0.f;
        if (l > 0) {
            #pragma unroll
            for (int k = 0; k < KNB; ++k) {
                float w = lg[k]*inv; int j = nb[k];
                mh += w * vfin[(size_t)j*64 + lane];
                b0 += w * vin[(size_t)j*64 + lane];
                b1 += w * vin[(size_t)N64 + (size_t)j*64 + lane];
                b2 += w * vin[2*(size_t)N64 + (size_t)j*64 + lane];
                s0 += w * dirn[ga*48 + k*3 + 0];
                s1 += w * dirn[ga*48 + k*3 + 1];
                s2 += w * dirn[ga*48 + k*3 + 2];
            }
            sVA[0][la*LDA + lane] = b0;
            sVA[1][la*LDA + lane] = b1;
            sVA[2][la*LDA + lane] = b2;
        } else {
            #pragma unroll
            for (int k = 0; k < KNB; ++k) {
                float w = lg[k]*inv; int j = nb[k];
                mh += w * vfin[(size_t)j*64 + lane];
                s0 += w * dirn[ga*48 + k*3 + 0];
                s1 += w * dirn[ga*48 + k*3 + 1];
                s2 += w * dirn[ga*48 + k*3 + 2];
            }
        }
        sM[la*LDU + lane] = mh;
        if ((lane & 7) == 0) {
            int hh = lane >> 3;
            sDS[la*24 + 0*8 + hh] = s0;
            sDS[la*24 + 1*8 + hh] = s1;
            sDS[la*24 + 2*8 + hh] = s2;
        }
    }
    __syncthreads();

    // ---- P2: s += msg @ Wo ----
    stageW(Wo_l); __syncthreads();
    {
        float4 c0 = *(float4*)(sS + gi*LDA + gj*4);
        float4 c1 = *(float4*)(sS + (gi+16)*LDA + gj*4);
        do_gemm(sM, LDU, 0, c0, c1);
        __syncthreads();
        *(float4*)(sS + gi*LDA + gj*4)      = c0;
        *(float4*)(sS + (gi+16)*LDA + gj*4) = c1;
    }
    __syncthreads();

    // ---- P3: h2 = LN(s) ----
    do_ln(sS, sH);
    __syncthreads();

    // ---- P4: gate + vector update ----
    stageW(Wg_l); __syncthreads();
    {
        float4 g0 = make_float4(0,0,0,0), g1 = g0;
        do_gemm(sH, LDA, 0, g0, g1);
        g0.x=sigmoid_f(g0.x); g0.y=sigmoid_f(g0.y); g0.z=sigmoid_f(g0.z); g0.w=sigmoid_f(g0.w);
        g1.x=sigmoid_f(g1.x); g1.y=sigmoid_f(g1.y); g1.z=sigmoid_f(g1.z); g1.w=sigmoid_f(g1.w);
        __syncthreads();
        stageW(Wc_l); __syncthreads();
        float4 wd4 = *(const float4*)&wd_l[gj*4];
        int g0i = a0+gi, g1i = a0+gi+16;
        #pragma unroll
        for (int p = 0; p < 3; ++p) {
            float4 t0 = make_float4(0,0,0,0), t1 = t0;
            if (l > 0) do_gemm(sVA[p], LDA, 0, t0, t1);
            float sp0 = sDS[gi*24 + p*8 + (gj>>1)];
            float sp1 = sDS[(gi+16)*24 + p*8 + (gj>>1)];
            if (g0i < NN) {
                float4 vi = make_float4(0,0,0,0);
                if (l > 0) vi = *(const float4*)(vin + (size_t)p*N64 + (size_t)g0i*64 + gj*4);
                float4 o;
                o.x = (vi.x + t0.x + wd4.x*sp0)*g0.x;
                o.y = (vi.y + t0.y + wd4.y*sp0)*g0.y;
                o.z = (vi.z + t0.z + wd4.z*sp0)*g0.z;
                o.w = (vi.w + t0.w + wd4.w*sp0)*g0.w;
                *(float4*)(vout + (size_t)p*N64 + (size_t)g0i*64 + gj*4) = o;
            }
            if (g1i < NN) {
                float4 vi = make_float4(0,0,0,0);
                if (l > 0) vi = *(const float4*)(vin + (size_t)p*N64 + (size_t)g1i*64 + gj*4);
                float4 o;
                o.x = (vi.x + t1.x + wd4.x*sp1)*g1.x;
                o.y = (vi.y + t1.y + wd4.y*sp1)*g1.y;
                o.z = (vi.z + t1.z + wd4.z*sp1)*g1.z;
                o.w = (vi.w + t1.w + wd4.w*sp1)*g1.w;
                *(float4*)(vout + (size_t)p*N64 + (size_t)g1i*64 + gj*4) = o;
            }
        }
    }
    __syncthreads();

    // ---- P5: FFN ----
    stageW1h(W1_l, 0); __syncthreads();
    {
        float4 c0 = make_float4(0,0,0,0), c1 = c0;
        do_gemm(sH, LDA, 0, c0, c1);
        c0.x=gelu_f(c0.x); c0.y=gelu_f(c0.y); c0.z=gelu_f(c0.z); c0.w=gelu_f(c0.w);
        c1.x=gelu_f(c1.x); c1.y=gelu_f(c1.y); c1.z=gelu_f(c1.z); c1.w=gelu_f(c1.w);
        __syncthreads();
        *(float4*)(sM + gi*LDU + gj*4)      = c0;
        *(float4*)(sM + (gi+16)*LDU + gj*4) = c1;
    }
    __syncthreads();
    stageW1h(W1_l, 1); __syncthreads();
    {
        float4 c0 = make_float4(0,0,0,0), c1 = c0;
        do_gemm(sH, LDA, 0, c0, c1);
        c0.x=gelu_f(c0.x); c0.y=gelu_f(c0.y); c0.z=gelu_f(c0.z); c0.w=gelu_f(c0.w);
        c1.x=gelu_f(c1.x); c1.y=gelu_f(c1.y); c1.z=gelu_f(c1.z); c1.w=gelu_f(c1.w);
        __syncthreads();
        *(float4*)(sM + gi*LDU + 64 + gj*4)      = c0;
        *(float4*)(sM + (gi+16)*LDU + 64 + gj*4) = c1;
    }
    __syncthreads();
    stageW(W2_l); __syncthreads();
    {
        float4 c0 = *(float4*)(sS + gi*LDA + gj*4);
        float4 c1 = *(float4*)(sS + (gi+16)*LDA + gj*4);
        do_gemm(sM, LDU, 0, c0, c1);
        __syncthreads();
        stageW(W2_l + 4096); __syncthreads();
        do_gemm(sM, LDU, 64, c0, c1);
        __syncthreads();
        *(float4*)(sS + gi*LDA + gj*4)      = c0;
        *(float4*)(sS + (gi+16)*LDA + gj*4) = c1;
    }
    __syncthreads();

    // ---- P6: next-layer q/k/vf  (or pooling for last layer) ----
    if (l < LAYERS-1) {
        do_ln(sS, sH);
        __syncthreads();
        stageW(Wk + (l+1)*4096); __syncthreads();
        { float4 c0 = make_float4(0,0,0,0), c1 = c0; do_gemm(sH, LDA, 0, c0, c1); store_g(kout, c0, c1); }
        __syncthreads();
        stageW(Wv + (l+1)*4096); __syncthreads();
        { float4 c0 = make_float4(0,0,0,0), c1 = c0; do_gemm(sH, LDA, 0, c0, c1); store_g(vfout, c0, c1); }
        __syncthreads();
        stageW(Wq + (l+1)*4096); __syncthreads();
        { float4 c0 = make_float4(0,0,0,0), c1 = c0; do_gemm(sH, LDA, 0, c0, c1); store_g(qout, c0, c1); }
        // write s back
        {
            int ga = a0 + lrow;
            if (ga < NN) {
                float4* dp = (float4*)(sg + (size_t)ga*64);
                const float4* sp = (const float4*)(sS + lrow*LDA);
                dp[lsub*2] = sp[lsub*2]; dp[lsub*2+1] = sp[lsub*2+1];
            }
        }
    } else {
        int ga = a0 + lrow;
        if (ga < NN) {
            int r = ridx[ga];
            #pragma unroll
            for (int e = 0; e < 8; ++e)
                atomicAdd(&resb[r*64 + lsub*8 + e], sS[lrow*LDA + lsub*8 + e]);
        }
    }
}

// ---------------- head ----------------
__global__ void head_kernel(const float* __restrict__ res, const float* __restrict__ Wout,
                            const float* __restrict__ bout, float* __restrict__ out, int r_total) {
    int wave = threadIdx.x >> 6, lane = threadIdx.x & 63;
    int r = blockIdx.x*4 + wave;
    if (r >= r_total) return;
    float p = res[r*HID + lane] * (1.0f/APR);
    float o0 = p * Wout[lane*2 + 0];
    float o1 = p * Wout[lane*2 + 1];
    #pragma unroll
    for (int off = 1; off < 64; off <<= 1) { o0 += __shfl_xor(o0, off); o1 += __shfl_xor(o1, off); }
    if (lane == 0) { out[r*2+0] = o0 + bout[0]; out[r*2+1] = o1 + bout[1]; }
}

// ---------------- launcher ----------------
extern "C" void kernel_launch(void* const* d_in, const int* in_sizes, int n_in,
                              void* d_out, int out_size, void* d_ws, size_t ws_size,
                              hipStream_t stream) {
    const float* coords    = (const float*)d_in[0];
    const int*   atom_ids  = (const int*)d_in[1];
    const int*   res_ids   = (const int*)d_in[2];
    const int*   elem_ids  = (const int*)d_in[3];
    const int*   ridx      = (const int*)d_in[4];
    const float* emb_atom  = (const float*)d_in[5];
    const float* emb_res   = (const float*)d_in[6];
    const float* emb_elem  = (const float*)d_in[7];
    const float* Win       = (const float*)d_in[8];
    const float* Wq        = (const float*)d_in[9];
    const float* Wk        = (const float*)d_in[10];
    const float* Wv        = (const float*)d_in[11];
    const float* Wvec      = (const float*)d_in[12];
    const float* wdir      = (const float*)d_in[13];
    const float* dist_bias = (const float*)d_in[14];
    const float* Wo        = (const float*)d_in[15];
    const float* W1        = (const float*)d_in[16];
    const float* W2        = (const float*)d_in[17];
    const float* Wg        = (const float*)d_in[18];
    const float* Wout      = (const float*)d_in[19];
    const float* bout      = (const float*)d_in[20];
    float* out = (float*)d_out;

    float* ws = (float*)d_ws;
    float* qA = ws + OFF_QA;  float* kA = ws + OFF_KA;  float* fA = ws + OFF_FA;
    float* qB = ws + OFF_QB;  float* kB = ws + OFF_KB;  float* fB = ws + OFF_FB;
    float* vA = ws + OFF_VA;  float* vB = ws + OFF_VB;
    float* sg = ws + OFF_S;
    float* dirn = ws + OFF_DIRN;
    float4* c4  = (float4*)(ws + OFF_C4);
    float* resb = ws + OFF_RES;
    int* nbr    = (int*)(ws + OFF_NBR);
    int* binsb  = (int*)(ws + OFF_BINS);

    hipMemsetAsync(resb, 0, (size_t)RR*HID*sizeof(float), stream);

    pad4_kernel<<<(NN+255)/256, 256, 0, stream>>>(coords, c4, NN);
    knn_kernel<<<(NN+15)/16, 1024, 0, stream>>>(c4, nbr, binsb, dirn, NN);
    prologue_kernel<<<NBLK, 256, 0, stream>>>(atom_ids, res_ids, elem_ids,
                                              emb_atom, emb_res, emb_elem,
                                              Win, Wq, Wk, Wv, sg, qA, kA, fA);
    for (int l = 0; l < LAYERS; ++l) {
        int p = l & 1;
        const float* qin = p ? qB : qA;  float* qout = p ? qA : qB;
        const float* kin = p ? kB : kA;  float* kout = p ? kA : kB;
        const float* fin = p ? fB : fA;  float* fout = p ? fA : fB;
        const float* vin = p ? vB : vA;  float* vout = p ? vA : vB;
        layer_kernel<<<NBLK, 256, 0, stream>>>(qin, kin, fin, qout, kout, fout,
                                               vin, vout, sg, dirn, nbr, binsb,
                                               resb, ridx,
                                               Wvec, wdir, dist_bias,
                                               Wo, W1, W2, Wg, Wq, Wk, Wv, l);
    }
    head_kernel<<<(RR+3)/4, 256, 0, stream>>>(resb, Wout, bout, out, RR);
}